// Round 1
// baseline (588.750 us; speedup 1.0000x reference)
//
#include <hip/hip_runtime.h>
#include <hip/hip_bf16.h>
#include <math.h>

#define BB 8
#define TT 1024
#define DD 256
#define HH 8
#define DKK 32
#define FFD 1024
#define BT 8192   // B*T

typedef __attribute__((ext_vector_type(4))) float f32x4;
typedef __attribute__((ext_vector_type(8))) short short8;
typedef __attribute__((ext_vector_type(8))) __bf16 bf16x8;

__device__ inline float bf2f(short s) {
  unsigned int u = ((unsigned int)(unsigned short)s) << 16;
  return __builtin_bit_cast(float, u);
}
__device__ inline short f2bf(float f) {
  unsigned int u = __builtin_bit_cast(unsigned int, f);
  unsigned int lsb = (u >> 16) & 1u;
  u += 0x7fffu + lsb;
  return (short)(u >> 16);
}

__device__ inline f32x4 mfma16(short8 a, short8 b, f32x4 c) {
  return __builtin_amdgcn_mfma_f32_16x16x32_bf16(
      __builtin_bit_cast(bf16x8, a), __builtin_bit_cast(bf16x8, b), c, 0, 0, 0);
}

__device__ inline void gload_lds16(void* lds, const void* g) {
  __builtin_amdgcn_global_load_lds(
      (const __attribute__((address_space(1))) unsigned int*)g,
      (__attribute__((address_space(3))) unsigned int*)lds, 16, 0, 0);
}

// ---------------- weight fp32 -> bf16 convert ----------------
__global__ void cvt_kernel(const float* __restrict__ src, short* __restrict__ dst, int n) {
  int i = blockIdx.x * 256 + threadIdx.x;
  if (i < n) dst[i] = f2bf(src[i]);
}

// ---------------- LayerNorm (optionally double LN) ----------------
// one row (256 f32) per 64-lane wave, 4 rows per block
__global__ __launch_bounds__(256) void ln_kernel(
    const float* __restrict__ Xin,
    const float* __restrict__ g1, const float* __restrict__ b1,
    const float* __restrict__ g2, const float* __restrict__ b2,
    short* __restrict__ out, int dbl)
{
  const int row = blockIdx.x * 4 + (threadIdx.x >> 6);
  const int lane = threadIdx.x & 63;
  const float4 v = *(const float4*)(Xin + (size_t)row * 256 + lane * 4);
  float y[4] = {v.x, v.y, v.z, v.w};

  float s = y[0] + y[1] + y[2] + y[3];
  #pragma unroll
  for (int m = 32; m >= 1; m >>= 1) s += __shfl_xor(s, m, 64);
  float mean = s * (1.0f / 256.0f);
  float sq = 0.f;
  #pragma unroll
  for (int i = 0; i < 4; ++i) { y[i] -= mean; sq += y[i] * y[i]; }
  #pragma unroll
  for (int m = 32; m >= 1; m >>= 1) sq += __shfl_xor(sq, m, 64);
  float rs = rsqrtf(sq * (1.0f / 256.0f) + 1e-6f);
  #pragma unroll
  for (int i = 0; i < 4; ++i) y[i] = y[i] * rs * g1[lane * 4 + i] + b1[lane * 4 + i];

  if (dbl) {
    float s2 = y[0] + y[1] + y[2] + y[3];
    #pragma unroll
    for (int m = 32; m >= 1; m >>= 1) s2 += __shfl_xor(s2, m, 64);
    float m2 = s2 * (1.0f / 256.0f);
    float sq2 = 0.f;
    #pragma unroll
    for (int i = 0; i < 4; ++i) { y[i] -= m2; sq2 += y[i] * y[i]; }
    #pragma unroll
    for (int m = 32; m >= 1; m >>= 1) sq2 += __shfl_xor(sq2, m, 64);
    float rs2 = rsqrtf(sq2 * (1.0f / 256.0f) + 1e-6f);
    #pragma unroll
    for (int i = 0; i < 4; ++i) y[i] = y[i] * rs2 * g2[lane * 4 + i] + b2[lane * 4 + i];
  }
  #pragma unroll
  for (int i = 0; i < 4; ++i) out[(size_t)row * 256 + lane * 4 + i] = f2bf(y[i]);
}

// ---------------- GEMM: C[M,N] = A[M,K] @ Bw[N,K]^T (+epilogue) ----------------
// EPI 0: Out_bf = bf16(acc + bias)                       (QKV)
// EPI 1: X += tanh(sc)*((acc+bias)*0.5)                  (Wo residual)
// EPI 2: Out_bf = bf16(gelu_exact(acc + bias))           (FFN1)
// EPI 3: X = clip(X + tanh(sc)*(acc+bias), +-100)        (FFN2 residual)
template<int EPI>
__global__ __launch_bounds__(256) void gemm_bt(
    const short* __restrict__ A, const short* __restrict__ Bw,
    const float* __restrict__ bias, float* __restrict__ X,
    short* __restrict__ Obf, const float* __restrict__ scale_p,
    int M, int N, int K)
{
  __shared__ __align__(16) short A_s[128 * 32];
  __shared__ __align__(16) short B_s[128 * 32];
  const int tid = threadIdx.x;
  const int lane = tid & 63;
  const int w = tid >> 6;
  const int wm = w >> 1, wn = w & 1;
  const int tM = blockIdx.y * 128, tN = blockIdx.x * 128;

  f32x4 acc[4][4];
  #pragma unroll
  for (int i = 0; i < 4; ++i)
    #pragma unroll
    for (int j = 0; j < 4; ++j) acc[i][j] = (f32x4){0.f, 0.f, 0.f, 0.f};

  const int srow = lane >> 2;        // 0..15 row within 16-row group
  const int skel = (lane & 3) * 8;   // k element offset

  for (int k0 = 0; k0 < K; k0 += 32) {
    #pragma unroll
    for (int i = 0; i < 2; ++i) {
      int row = w * 32 + i * 16 + srow;
      gload_lds16(&A_s[(w * 2 + i) * 512], A + (size_t)(tM + row) * K + k0 + skel);
      gload_lds16(&B_s[(w * 2 + i) * 512], Bw + (size_t)(tN + row) * K + k0 + skel);
    }
    __syncthreads();
    short8 af[4], bfr[4];
    #pragma unroll
    for (int i = 0; i < 4; ++i)
      af[i] = *(const short8*)&A_s[(wm * 64 + i * 16 + (lane & 15)) * 32 + (lane >> 4) * 8];
    #pragma unroll
    for (int j = 0; j < 4; ++j)
      bfr[j] = *(const short8*)&B_s[(wn * 64 + j * 16 + (lane & 15)) * 32 + (lane >> 4) * 8];
    #pragma unroll
    for (int i = 0; i < 4; ++i)
      #pragma unroll
      for (int j = 0; j < 4; ++j)
        acc[i][j] = mfma16(af[i], bfr[j], acc[i][j]);
    __syncthreads();
  }

  float ts = 0.f;
  if (EPI == 1 || EPI == 3) ts = tanhf(scale_p[0]);

  #pragma unroll
  for (int i = 0; i < 4; ++i) {
    #pragma unroll
    for (int j = 0; j < 4; ++j) {
      #pragma unroll
      for (int r = 0; r < 4; ++r) {
        int row = tM + wm * 64 + i * 16 + (lane >> 4) * 4 + r;
        int col = tN + wn * 64 + j * 16 + (lane & 15);
        float v = acc[i][j][r] + bias[col];
        size_t idx = (size_t)row * N + col;
        if (EPI == 0) {
          Obf[idx] = f2bf(v);
        } else if (EPI == 1) {
          X[idx] += ts * (v * 0.5f);
        } else if (EPI == 2) {
          float gl = 0.5f * v * (1.0f + erff(v * 0.70710678118f));
          Obf[idx] = f2bf(gl);
        } else {
          float o = X[idx] + ts * v;
          o = fminf(100.f, fmaxf(-100.f, o));
          X[idx] = o;
        }
      }
    }
  }
}

// ---------------- fused causal attention ----------------
// qkv: [BT][768] bf16, rows = [Q(256) | K(256) | V(256)], head h at h*32
// includes per-head l2norm of Q and K. scores clipped to +-10 -> direct exp, no online max.
__global__ __launch_bounds__(256) void attn_kernel(
    const short* __restrict__ qkv, const unsigned char* __restrict__ pad,
    short* __restrict__ ao)
{
  __shared__ __align__(16) short Ks[64 * 32];
  __shared__ __align__(16) short Vt[32 * 64];
  __shared__ __align__(16) short Pl[4][16 * 64];
  const float SCALE = 0.17677669529663687f;  // 1/sqrt(32)

  const int tid = threadIdx.x, lane = tid & 63, w = tid >> 6;
  const int qt = blockIdx.x;       // query tile 0..15 (64 queries)
  const int bh = blockIdx.y;       // 0..63
  const int b = bh >> 3, h = bh & 7;
  const int qbase = qt * 64 + w * 16;

  // --- load + l2norm Q fragment (A-frag: row=lane&15, k=(lane>>4)*8..+7) ---
  const int qrow = qbase + (lane & 15);
  short8 qf = *(const short8*)(qkv + (size_t)(b * TT + qrow) * 768 + h * 32 + (lane >> 4) * 8);
  float qv[8]; float qs = 0.f;
  #pragma unroll
  for (int j = 0; j < 8; ++j) { qv[j] = bf2f(qf[j]); qs += qv[j] * qv[j]; }
  qs += __shfl_xor(qs, 16, 64);
  qs += __shfl_xor(qs, 32, 64);
  float qinv = 1.0f / fmaxf(sqrtf(qs), 1e-8f);
  #pragma unroll
  for (int j = 0; j < 8; ++j) qf[j] = f2bf(qv[j] * qinv);

  f32x4 aof[2];
  aof[0] = (f32x4){0.f, 0.f, 0.f, 0.f};
  aof[1] = (f32x4){0.f, 0.f, 0.f, 0.f};
  float rsum[4] = {0.f, 0.f, 0.f, 0.f};

  const int krow = tid >> 2;          // 0..63 local key
  const int kd = (tid & 3) * 8;       // d part

  for (int c = 0; c <= qt; ++c) {
    __syncthreads();   // previous iter's Ks/Vt reads done before overwrite
    const int key = c * 64 + krow;
    // K: load 8 elems, l2norm across the 4 lanes sharing this key row, store
    short8 kv = *(const short8*)(qkv + (size_t)(b * TT + key) * 768 + 256 + h * 32 + kd);
    float kf[8]; float kss = 0.f;
    #pragma unroll
    for (int j = 0; j < 8; ++j) { kf[j] = bf2f(kv[j]); kss += kf[j] * kf[j]; }
    kss += __shfl_xor(kss, 1, 64);
    kss += __shfl_xor(kss, 2, 64);
    float kinv = 1.0f / fmaxf(sqrtf(kss), 1e-8f);
    short8 kn;
    #pragma unroll
    for (int j = 0; j < 8; ++j) kn[j] = f2bf(kf[j] * kinv);
    *(short8*)&Ks[krow * 32 + kd] = kn;
    // V: load + transposed store (Vt[d][key])
    short8 vv = *(const short8*)(qkv + (size_t)(b * TT + key) * 768 + 512 + h * 32 + kd);
    #pragma unroll
    for (int j = 0; j < 8; ++j) Vt[(kd + j) * 64 + krow] = vv[j];
    __syncthreads();

    // S = Q K^T (4 key-subtiles of 16), then P = exp(clip(S*scale)) with masks
    #pragma unroll
    for (int kk = 0; kk < 4; ++kk) {
      short8 bfr = *(const short8*)&Ks[(kk * 16 + (lane & 15)) * 32 + (lane >> 4) * 8];
      f32x4 sf = mfma16(qf, bfr, (f32x4){0.f, 0.f, 0.f, 0.f});
      const int kg = c * 64 + kk * 16 + (lane & 15);
      const bool padk = pad[b * TT + kg] != 0;
      #pragma unroll
      for (int r = 0; r < 4; ++r) {
        const int qg = qbase + (lane >> 4) * 4 + r;
        float s = sf[r] * SCALE;
        s = fminf(10.f, fmaxf(-10.f, s));
        float p = (kg > qg || padk) ? 0.f : __expf(s);
        rsum[r] += p;
        Pl[w][((lane >> 4) * 4 + r) * 64 + kk * 16 + (lane & 15)] = f2bf(p);
      }
    }
    __syncthreads();

    // PV: ao[16q x 32d] += P[16 x 64] @ V[64 x 32]
    #pragma unroll
    for (int k2 = 0; k2 < 2; ++k2) {
      short8 pf = *(const short8*)&Pl[w][(lane & 15) * 64 + k2 * 32 + (lane >> 4) * 8];
      #pragma unroll
      for (int n = 0; n < 2; ++n) {
        short8 vf = *(const short8*)&Vt[(n * 16 + (lane & 15)) * 64 + k2 * 32 + (lane >> 4) * 8];
        aof[n] = mfma16(pf, vf, aof[n]);
      }
    }
  }

  // reduce row sums across the 16 lanes of each row group
  #pragma unroll
  for (int r = 0; r < 4; ++r) {
    #pragma unroll
    for (int m = 1; m <= 8; m <<= 1) rsum[r] += __shfl_xor(rsum[r], m, 64);
  }
  #pragma unroll
  for (int r = 0; r < 4; ++r) {
    const int q = qbase + (lane >> 4) * 4 + r;
    float inv = 1.0f / fmaxf(rsum[r], 1e-30f);
    #pragma unroll
    for (int n = 0; n < 2; ++n) {
      ao[(size_t)(b * TT + q) * 256 + h * 32 + n * 16 + (lane & 15)] = f2bf(aof[n][r] * inv);
    }
  }
}

extern "C" void kernel_launch(void* const* d_in, const int* in_sizes, int n_in,
                              void* d_out, int out_size, void* d_ws, size_t ws_size,
                              hipStream_t stream) {
  const float* x_in  = (const float*)d_in[0];
  const unsigned char* pad = (const unsigned char*)d_in[1];
  const float* ln1_g = (const float*)d_in[2];
  const float* ln1_b = (const float*)d_in[3];
  const float* qn_g  = (const float*)d_in[4];
  const float* qn_b  = (const float*)d_in[5];
  const float* Wqkv  = (const float*)d_in[6];
  const float* bqkv  = (const float*)d_in[7];
  const float* Wo    = (const float*)d_in[8];
  const float* bo    = (const float*)d_in[9];
  const float* ln2_g = (const float*)d_in[10];
  const float* ln2_b = (const float*)d_in[11];
  const float* W1    = (const float*)d_in[12];
  const float* b1    = (const float*)d_in[13];
  const float* W2    = (const float*)d_in[14];
  const float* b2    = (const float*)d_in[15];
  const float* alpha = (const float*)d_in[16];
  const float* beta  = (const float*)d_in[17];

  char* ws = (char*)d_ws;
  size_t off = 0;
  short* wqkv_bf = (short*)(ws + off); off += (size_t)4 * 768 * 256 * 2;   // 1572864
  short* wo_bf   = (short*)(ws + off); off += (size_t)4 * 256 * 256 * 2;   // 524288
  short* w1_bf   = (short*)(ws + off); off += (size_t)4 * 1024 * 256 * 2;  // 2097152
  short* w2_bf   = (short*)(ws + off); off += (size_t)4 * 256 * 1024 * 2;  // 2097152
  short* h_bf    = (short*)(ws + off); off += (size_t)BT * 256 * 2;        // 4194304
  short* qkv_bf  = (short*)(ws + off); off += (size_t)BT * 768 * 2;        // 12582912
  short* ao_bf   = (short*)(ws + off); off += (size_t)BT * 256 * 2;        // 4194304
  short* g_bf    = (short*)(ws + off); off += (size_t)BT * 1024 * 2;       // 16777216

  float* X = (float*)d_out;

  hipMemcpyAsync(d_out, x_in, (size_t)BT * DD * 4, hipMemcpyDeviceToDevice, stream);
  cvt_kernel<<<3072, 256, 0, stream>>>(Wqkv, wqkv_bf, 4 * 768 * 256);
  cvt_kernel<<<1024, 256, 0, stream>>>(Wo,   wo_bf,   4 * 256 * 256);
  cvt_kernel<<<4096, 256, 0, stream>>>(W1,   w1_bf,   4 * 1024 * 256);
  cvt_kernel<<<4096, 256, 0, stream>>>(W2,   w2_bf,   4 * 256 * 1024);

  for (int l = 0; l < 4; ++l) {
    ln_kernel<<<2048, 256, 0, stream>>>(X, ln1_g + l * 256, ln1_b + l * 256,
                                        qn_g + l * 256, qn_b + l * 256, h_bf, 1);
    gemm_bt<0><<<dim3(6, 64), 256, 0, stream>>>(h_bf, wqkv_bf + (size_t)l * 768 * 256,
                                                bqkv + l * 768, nullptr, qkv_bf, nullptr,
                                                8192, 768, 256);
    attn_kernel<<<dim3(16, 64), 256, 0, stream>>>(qkv_bf, pad, ao_bf);
    gemm_bt<1><<<dim3(2, 64), 256, 0, stream>>>(ao_bf, wo_bf + (size_t)l * 256 * 256,
                                                bo + l * 256, X, nullptr, alpha + l,
                                                8192, 256, 256);
    ln_kernel<<<2048, 256, 0, stream>>>(X, ln2_g + l * 256, ln2_b + l * 256,
                                        nullptr, nullptr, h_bf, 0);
    gemm_bt<2><<<dim3(8, 64), 256, 0, stream>>>(h_bf, w1_bf + (size_t)l * 1024 * 256,
                                                b1 + l * 1024, nullptr, g_bf, nullptr,
                                                8192, 1024, 256);
    gemm_bt<3><<<dim3(2, 64), 256, 0, stream>>>(g_bf, w2_bf + (size_t)l * 256 * 1024,
                                                b2 + l * 256, X, nullptr, beta + l,
                                                8192, 256, 1024);
  }
}

// Round 2
// 520.797 us; speedup vs baseline: 1.1305x; 1.1305x over previous
//
#include <hip/hip_runtime.h>
#include <hip/hip_bf16.h>
#include <math.h>

#define BB 8
#define TT 1024
#define DD 256
#define HH 8
#define BT 8192   // B*T

typedef __attribute__((ext_vector_type(4))) float f32x4;
typedef __attribute__((ext_vector_type(16))) float f32x16;
typedef __attribute__((ext_vector_type(8))) short short8;
typedef __attribute__((ext_vector_type(4))) short short4v;
typedef __attribute__((ext_vector_type(8))) __bf16 bf16x8;

__device__ inline float bf2f(short s) {
  unsigned int u = ((unsigned int)(unsigned short)s) << 16;
  return __builtin_bit_cast(float, u);
}
__device__ inline short f2bf(float f) {
  unsigned int u = __builtin_bit_cast(unsigned int, f);
  unsigned int lsb = (u >> 16) & 1u;
  u += 0x7fffu + lsb;
  return (short)(u >> 16);
}
__device__ inline unsigned int cvtpk(float lo, float hi) {
  unsigned int r;
  asm("v_cvt_pk_bf16_f32 %0, %1, %2" : "=v"(r) : "v"(lo), "v"(hi));
  return r;
}

__device__ inline f32x4 mfma16(short8 a, short8 b, f32x4 c) {
  return __builtin_amdgcn_mfma_f32_16x16x32_bf16(
      __builtin_bit_cast(bf16x8, a), __builtin_bit_cast(bf16x8, b), c, 0, 0, 0);
}
__device__ inline f32x16 mfma32(short8 a, short8 b, f32x16 c) {
  return __builtin_amdgcn_mfma_f32_32x32x16_bf16(
      __builtin_bit_cast(bf16x8, a), __builtin_bit_cast(bf16x8, b), c, 0, 0, 0);
}

__device__ inline void gload_lds16(void* lds, const void* g) {
  __builtin_amdgcn_global_load_lds(
      (const __attribute__((address_space(1))) unsigned int*)g,
      (__attribute__((address_space(3))) unsigned int*)lds, 16, 0, 0);
}

// ---------------- weight fp32 -> bf16 convert (vectorized) ----------------
__global__ void cvt_kernel(const float4* __restrict__ src, short4v* __restrict__ dst, int n4) {
  int i = blockIdx.x * 256 + threadIdx.x;
  if (i < n4) {
    float4 v = src[i];
    short4v o;
    o[0] = f2bf(v.x); o[1] = f2bf(v.y); o[2] = f2bf(v.z); o[3] = f2bf(v.w);
    dst[i] = o;
  }
}

// ---------------- LayerNorm (optionally double LN) ----------------
__global__ __launch_bounds__(256) void ln_kernel(
    const float* __restrict__ Xin,
    const float* __restrict__ g1, const float* __restrict__ b1,
    const float* __restrict__ g2, const float* __restrict__ b2,
    short* __restrict__ out, int dbl)
{
  const int row = blockIdx.x * 4 + (threadIdx.x >> 6);
  const int lane = threadIdx.x & 63;
  const float4 v = *(const float4*)(Xin + (size_t)row * 256 + lane * 4);
  float y[4] = {v.x, v.y, v.z, v.w};

  float s = y[0] + y[1] + y[2] + y[3];
  #pragma unroll
  for (int m = 32; m >= 1; m >>= 1) s += __shfl_xor(s, m, 64);
  float mean = s * (1.0f / 256.0f);
  float sq = 0.f;
  #pragma unroll
  for (int i = 0; i < 4; ++i) { y[i] -= mean; sq += y[i] * y[i]; }
  #pragma unroll
  for (int m = 32; m >= 1; m >>= 1) sq += __shfl_xor(sq, m, 64);
  float rs = rsqrtf(sq * (1.0f / 256.0f) + 1e-6f);
  #pragma unroll
  for (int i = 0; i < 4; ++i) y[i] = y[i] * rs * g1[lane * 4 + i] + b1[lane * 4 + i];

  if (dbl) {
    float s2 = y[0] + y[1] + y[2] + y[3];
    #pragma unroll
    for (int m = 32; m >= 1; m >>= 1) s2 += __shfl_xor(s2, m, 64);
    float m2 = s2 * (1.0f / 256.0f);
    float sq2 = 0.f;
    #pragma unroll
    for (int i = 0; i < 4; ++i) { y[i] -= m2; sq2 += y[i] * y[i]; }
    #pragma unroll
    for (int m = 32; m >= 1; m >>= 1) sq2 += __shfl_xor(sq2, m, 64);
    float rs2 = rsqrtf(sq2 * (1.0f / 256.0f) + 1e-6f);
    #pragma unroll
    for (int i = 0; i < 4; ++i) y[i] = y[i] * rs2 * g2[lane * 4 + i] + b2[lane * 4 + i];
  }
  #pragma unroll
  for (int i = 0; i < 4; ++i) out[(size_t)row * 256 + lane * 4 + i] = f2bf(y[i]);
}

// ---------------- Q/K l2norm prepass (in place on qkv_bf) ----------------
// wave per token row; lanes 0..63 cover the 512 Q|K elements; head = lane>>2
__global__ __launch_bounds__(256) void qknorm_kernel(short* __restrict__ qkv) {
  const int row = blockIdx.x * 4 + (threadIdx.x >> 6);
  const int lane = threadIdx.x & 63;
  short* p = qkv + (size_t)row * 768 + lane * 8;
  short8 v = *(short8*)p;
  float f[8]; float ss = 0.f;
  #pragma unroll
  for (int j = 0; j < 8; ++j) { f[j] = bf2f(v[j]); ss += f[j] * f[j]; }
  ss += __shfl_xor(ss, 1, 64);
  ss += __shfl_xor(ss, 2, 64);
  float inv = 1.0f / fmaxf(sqrtf(ss), 1e-8f);
  short8 o;
  #pragma unroll
  for (int j = 0; j < 8; ++j) o[j] = f2bf(f[j] * inv);
  *(short8*)p = o;
}

// ---------------- GEMM: C[M,N] = A[M,K] @ Bw[N,K]^T (+epilogue) ----------------
// BM=128, BK=64, 4 waves. BN=128: 2x2 wave grid; BN=64: 4x1 wave grid.
// EPI 0: Out_bf = bf16(acc + bias)                       (QKV)
// EPI 1: X += tanh(sc)*((acc+bias)*0.5)                  (Wo residual)
// EPI 2: Out_bf = bf16(gelu_exact(acc + bias))           (FFN1)
// EPI 3: X = clip(X + tanh(sc)*(acc+bias), +-100)        (FFN2 residual)
template<int BN, int EPI>
__global__ __launch_bounds__(256) void gemm_bt(
    const short* __restrict__ A, const short* __restrict__ Bw,
    const float* __restrict__ bias, float* __restrict__ X,
    short* __restrict__ Obf, const float* __restrict__ scale_p,
    int M, int N, int K)
{
  constexpr int MI = (BN == 128) ? 4 : 2;   // 16-row frags per wave
  __shared__ __align__(16) short A_s[128 * 64];
  __shared__ __align__(16) short B_s[BN * 64];
  const int tid = threadIdx.x;
  const int lane = tid & 63;
  const int w = tid >> 6;
  const int lo4 = lane & 15, hi2 = lane >> 4;
  int wm, wn0;
  if (BN == 128) { wm = (w >> 1) * 64; wn0 = (w & 1) * 64; }
  else           { wm = w * 32;        wn0 = 0; }
  const int tM = blockIdx.y * 128, tN = blockIdx.x * BN;

  f32x4 acc[MI][4];
  #pragma unroll
  for (int i = 0; i < MI; ++i)
    #pragma unroll
    for (int j = 0; j < 4; ++j) acc[i][j] = (f32x4){0.f, 0.f, 0.f, 0.f};

  const int swz = (lo4 & 7) << 3;   // read-side XOR swizzle (shorts)

  for (int k0 = 0; k0 < K; k0 += 64) {
    // stage A: 4 rounds of 4KB; LDS dest is wave-linear, source pre-swizzled
    #pragma unroll
    for (int ri = 0; ri < 4; ++ri) {
      int o = ri * 2048 + tid * 8;
      int row = o >> 6;
      int col = (o & 63) ^ ((row & 7) << 3);
      gload_lds16(&A_s[ri * 2048 + w * 512], A + (size_t)(tM + row) * K + k0 + col);
    }
    #pragma unroll
    for (int ri = 0; ri < BN / 32; ++ri) {
      int o = ri * 2048 + tid * 8;
      int row = o >> 6;
      int col = (o & 63) ^ ((row & 7) << 3);
      gload_lds16(&B_s[ri * 2048 + w * 512], Bw + (size_t)(tN + row) * K + k0 + col);
    }
    __syncthreads();
    #pragma unroll
    for (int kc = 0; kc < 2; ++kc) {
      short8 af[MI], bfr[4];
      #pragma unroll
      for (int i = 0; i < MI; ++i)
        af[i] = *(const short8*)&A_s[(wm + i * 16 + lo4) * 64 + ((kc * 32 + hi2 * 8) ^ swz)];
      #pragma unroll
      for (int j = 0; j < 4; ++j)
        bfr[j] = *(const short8*)&B_s[(wn0 + j * 16 + lo4) * 64 + ((kc * 32 + hi2 * 8) ^ swz)];
      #pragma unroll
      for (int i = 0; i < MI; ++i)
        #pragma unroll
        for (int j = 0; j < 4; ++j)
          acc[i][j] = mfma16(af[i], bfr[j], acc[i][j]);
    }
    __syncthreads();
  }

  float ts = 0.f;
  if (EPI == 1 || EPI == 3) ts = tanhf(scale_p[0]);

  #pragma unroll
  for (int i = 0; i < MI; ++i) {
    #pragma unroll
    for (int j = 0; j < 4; ++j) {
      #pragma unroll
      for (int r = 0; r < 4; ++r) {
        int row = tM + wm + i * 16 + hi2 * 4 + r;
        int col = tN + wn0 + j * 16 + lo4;
        float v = acc[i][j][r] + bias[col];
        size_t idx = (size_t)row * N + col;
        if (EPI == 0) {
          Obf[idx] = f2bf(v);
        } else if (EPI == 1) {
          X[idx] += ts * (v * 0.5f);
        } else if (EPI == 2) {
          float gl = 0.5f * v * (1.0f + erff(v * 0.70710678118f));
          Obf[idx] = f2bf(gl);
        } else {
          float o = X[idx] + ts * v;
          o = fminf(100.f, fmaxf(-100.f, o));
          X[idx] = o;
        }
      }
    }
  }
}

// ---------------- fused causal attention, 32x32 MFMA, swapped QK^T ----------------
// qkv rows: [Qn(256) | Kn(256) | V(256)] bf16, Q/K pre-l2normed.
// Block = 4 waves; wave owns 32 queries. V staged in LDS (linear, dbuf); K from global.
__device__ void attn_qtile(const short* __restrict__ qkv,
                           const unsigned char* __restrict__ pad,
                           short* __restrict__ ao, short* V_s,
                           int b, int h, int qt2)
{
  const float SCALE = 0.17677669529663687f;  // 1/sqrt(32)
  const int tid = threadIdx.x, lane = tid & 63, w = tid >> 6;
  const int lo5 = lane & 31, hi1 = lane >> 5;
  const int qrow = qt2 * 128 + w * 32 + lo5;       // this lane's query (S^T col)
  const size_t rowbase = (size_t)b * TT;

  // Q b-frags: Brr[q=lo5][c2*16 + hi1*8 + j]
  short8 qb[2];
  #pragma unroll
  for (int c2 = 0; c2 < 2; ++c2)
    qb[c2] = *(const short8*)(qkv + (rowbase + qrow) * 768 + h * 32 + c2 * 16 + hi1 * 8);

  const int nt = (qt2 + 1) * 2;
  const int wq0 = qt2 * 128 + w * 32;
  const int maskT = wq0 >> 6;        // boundary tile for this wave; skip t > maskT

  f32x16 oacc = (f32x16)0.0f;
  float rsum = 0.f;

  const int skey = tid >> 2, sd = (tid & 3) * 8;   // V staging: lane-linear layout
  short8 vreg = *(const short8*)(qkv + (rowbase + skey) * 768 + 512 + h * 32 + sd);
  __syncthreads();                                  // protect V_s from previous q-tile readers
  *(short8*)&V_s[skey * 32 + sd] = vreg;

  for (int t = 0; t < nt; ++t) {
    __syncthreads();                                // V_s[t&1] visible
    if (t + 1 < nt)
      vreg = *(const short8*)(qkv + (rowbase + (t + 1) * 64 + skey) * 768 + 512 + h * 32 + sd);
    const short* Vb = V_s + (t & 1) * 2048;

    if (t <= maskT) {
      // ---- S^T = K·Q^T : 2 key-groups x 2 d-chunks ----
      f32x16 sa[2];
      #pragma unroll
      for (int kg = 0; kg < 2; ++kg) {
        const short* kp = qkv + (rowbase + t * 64 + kg * 32 + lo5) * 768 + 256 + h * 32;
        short8 kf0 = *(const short8*)(kp + hi1 * 8);
        short8 kf1 = *(const short8*)(kp + 16 + hi1 * 8);
        f32x16 z = (f32x16)0.0f;
        z = mfma32(kf0, qb[0], z);
        sa[kg] = mfma32(kf1, qb[1], z);
      }
      // ---- softmax numerator ----
      unsigned long long pm = __ballot(pad[rowbase + t * 64 + lane] != 0);
      const bool needMask = (t == maskT);
      const int qrel = qrow - t * 64;
      float p[2][16];
      #pragma unroll
      for (int kg = 0; kg < 2; ++kg) {
        #pragma unroll
        for (int r = 0; r < 16; ++r) {
          float sv = sa[kg][r] * SCALE;
          sv = fminf(10.f, fmaxf(-10.f, sv));
          float pe = __expf(sv);
          int key = kg * 32 + (r & 3) + 8 * (r >> 2) + 4 * hi1;  // tile-local key
          if (needMask) pe = (key > qrel) ? 0.f : pe;
          if (pm) pe = ((pm >> key) & 1ull) ? 0.f : pe;
          p[kg][r] = pe;
          rsum += pe;
        }
      }
      // ---- pack to bf16 pairs ----
      unsigned int pk[2][8];
      #pragma unroll
      for (int kg = 0; kg < 2; ++kg)
        #pragma unroll
        for (int i = 0; i < 8; ++i)
          pk[kg][i] = cvtpk(p[kg][2 * i], p[kg][2 * i + 1]);
      // ---- PV: 4 key-16 chunks; A-frag built via keep/send + shfl_xor(32) ----
      #pragma unroll
      for (int k2 = 0; k2 < 4; ++k2) {
        const int kg = k2 >> 1, half = k2 & 1;
        unsigned int keep0 = hi1 ? pk[kg][4 * half + 2] : pk[kg][4 * half + 0];
        unsigned int keep1 = hi1 ? pk[kg][4 * half + 3] : pk[kg][4 * half + 1];
        unsigned int send0 = hi1 ? pk[kg][4 * half + 0] : pk[kg][4 * half + 2];
        unsigned int send1 = hi1 ? pk[kg][4 * half + 1] : pk[kg][4 * half + 3];
        unsigned int r0 = (unsigned int)__shfl_xor((int)send0, 32, 64);
        unsigned int r1 = (unsigned int)__shfl_xor((int)send1, 32, 64);
        union { unsigned int u[4]; short8 s; } fa;
        fa.u[0] = hi1 ? r0 : keep0;
        fa.u[1] = hi1 ? r1 : keep1;
        fa.u[2] = hi1 ? keep0 : r0;
        fa.u[3] = hi1 ? keep1 : r1;
        // V b-frag: Brr[d=lo5][k] = V[key][d], scalar reads (2-way, free)
        short8 vb;
        #pragma unroll
        for (int j = 0; j < 8; ++j)
          vb[j] = Vb[(k2 * 16 + hi1 * 8 + j) * 32 + lo5];
        oacc = mfma32(fa.s, vb, oacc);
      }
    }
    if (t + 1 < nt)
      *(short8*)&V_s[((t + 1) & 1) * 2048 + skey * 32 + sd] = vreg;
  }

  // ---- finalize: rsum across halves, redistribute 1/rsum, store ----
  rsum += __shfl_xor(rsum, 32, 64);
  float rinv = 1.0f / fmaxf(rsum, 1e-30f);
  #pragma unroll
  for (int r = 0; r < 16; ++r) {
    int ql = (r & 3) + 8 * (r >> 2) + 4 * hi1;      // wave-local q of this acc reg
    float riv = __shfl(rinv, ql, 64);
    int qg = qt2 * 128 + w * 32 + ql;
    ao[(rowbase + qg) * 256 + h * 32 + lo5] = f2bf(oacc[r] * riv);
  }
}

__global__ __launch_bounds__(256) void attn_kernel(
    const short* __restrict__ qkv, const unsigned char* __restrict__ pad,
    short* __restrict__ ao)
{
  __shared__ __align__(16) short V_s[2 * 2048];
  const int jp = blockIdx.x;         // 0..3 -> q-tiles {jp, 7-jp} (load-balanced pair)
  const int bh = blockIdx.y;
  const int b = bh >> 3, h = bh & 7;
  attn_qtile(qkv, pad, ao, V_s, b, h, jp);
  attn_qtile(qkv, pad, ao, V_s, b, h, 7 - jp);
}

extern "C" void kernel_launch(void* const* d_in, const int* in_sizes, int n_in,
                              void* d_out, int out_size, void* d_ws, size_t ws_size,
                              hipStream_t stream) {
  const float* x_in  = (const float*)d_in[0];
  const unsigned char* pad = (const unsigned char*)d_in[1];
  const float* ln1_g = (const float*)d_in[2];
  const float* ln1_b = (const float*)d_in[3];
  const float* qn_g  = (const float*)d_in[4];
  const float* qn_b  = (const float*)d_in[5];
  const float* Wqkv  = (const float*)d_in[6];
  const float* bqkv  = (const float*)d_in[7];
  const float* Wo    = (const float*)d_in[8];
  const float* bo    = (const float*)d_in[9];
  const float* ln2_g = (const float*)d_in[10];
  const float* ln2_b = (const float*)d_in[11];
  const float* W1    = (const float*)d_in[12];
  const float* b1    = (const float*)d_in[13];
  const float* W2    = (const float*)d_in[14];
  const float* b2    = (const float*)d_in[15];
  const float* alpha = (const float*)d_in[16];
  const float* beta  = (const float*)d_in[17];

  char* ws = (char*)d_ws;
  size_t off = 0;
  short* wqkv_bf = (short*)(ws + off); off += (size_t)4 * 768 * 256 * 2;
  short* wo_bf   = (short*)(ws + off); off += (size_t)4 * 256 * 256 * 2;
  short* w1_bf   = (short*)(ws + off); off += (size_t)4 * 1024 * 256 * 2;
  short* w2_bf   = (short*)(ws + off); off += (size_t)4 * 256 * 1024 * 2;
  short* h_bf    = (short*)(ws + off); off += (size_t)BT * 256 * 2;
  short* qkv_bf  = (short*)(ws + off); off += (size_t)BT * 768 * 2;
  short* ao_bf   = (short*)(ws + off); off += (size_t)BT * 256 * 2;
  short* g_bf    = (short*)(ws + off); off += (size_t)BT * 1024 * 2;

  float* X = (float*)d_out;

  hipMemcpyAsync(d_out, x_in, (size_t)BT * DD * 4, hipMemcpyDeviceToDevice, stream);
  cvt_kernel<<<768,  256, 0, stream>>>((const float4*)Wqkv, (short4v*)wqkv_bf, 4 * 768 * 256 / 4);
  cvt_kernel<<<256,  256, 0, stream>>>((const float4*)Wo,   (short4v*)wo_bf,   4 * 256 * 256 / 4);
  cvt_kernel<<<1024, 256, 0, stream>>>((const float4*)W1,   (short4v*)w1_bf,   4 * 1024 * 256 / 4);
  cvt_kernel<<<1024, 256, 0, stream>>>((const float4*)W2,   (short4v*)w2_bf,   4 * 256 * 1024 / 4);

  for (int l = 0; l < 4; ++l) {
    ln_kernel<<<2048, 256, 0, stream>>>(X, ln1_g + l * 256, ln1_b + l * 256,
                                        qn_g + l * 256, qn_b + l * 256, h_bf, 1);
    gemm_bt<128, 0><<<dim3(6, 64), 256, 0, stream>>>(h_bf, wqkv_bf + (size_t)l * 768 * 256,
                                                     bqkv + l * 768, nullptr, qkv_bf, nullptr,
                                                     8192, 768, 256);
    qknorm_kernel<<<2048, 256, 0, stream>>>(qkv_bf);
    attn_kernel<<<dim3(4, 64), 256, 0, stream>>>(qkv_bf, pad, ao_bf);
    gemm_bt<64, 1><<<dim3(4, 64), 256, 0, stream>>>(ao_bf, wo_bf + (size_t)l * 256 * 256,
                                                    bo + l * 256, X, nullptr, alpha + l,
                                                    8192, 256, 256);
    ln_kernel<<<2048, 256, 0, stream>>>(X, ln2_g + l * 256, ln2_b + l * 256,
                                        nullptr, nullptr, h_bf, 0);
    gemm_bt<128, 2><<<dim3(8, 64), 256, 0, stream>>>(h_bf, w1_bf + (size_t)l * 1024 * 256,
                                                     b1 + l * 1024, nullptr, g_bf, nullptr,
                                                     8192, 1024, 256);
    gemm_bt<64, 3><<<dim3(4, 64), 256, 0, stream>>>(g_bf, w2_bf + (size_t)l * 256 * 1024,
                                                    b2 + l * 256, X, nullptr, beta + l,
                                                    8192, 256, 1024);
  }
}

// Round 3
// 479.895 us; speedup vs baseline: 1.2268x; 1.0852x over previous
//
#include <hip/hip_runtime.h>
#include <hip/hip_bf16.h>
#include <math.h>

#define BB 8
#define TT 1024
#define DD 256
#define HH 8
#define BT 8192   // B*T

typedef __attribute__((ext_vector_type(4))) float f32x4;
typedef __attribute__((ext_vector_type(16))) float f32x16;
typedef __attribute__((ext_vector_type(8))) short short8;
typedef __attribute__((ext_vector_type(4))) short short4v;
typedef __attribute__((ext_vector_type(8))) __bf16 bf16x8;

__device__ inline float bf2f(short s) {
  unsigned int u = ((unsigned int)(unsigned short)s) << 16;
  return __builtin_bit_cast(float, u);
}
__device__ inline short f2bf(float f) {
  unsigned int u = __builtin_bit_cast(unsigned int, f);
  unsigned int lsb = (u >> 16) & 1u;
  u += 0x7fffu + lsb;
  return (short)(u >> 16);
}
__device__ inline unsigned int cvtpk(float lo, float hi) {
  unsigned int r;
  asm("v_cvt_pk_bf16_f32 %0, %1, %2" : "=v"(r) : "v"(lo), "v"(hi));
  return r;
}

__device__ inline f32x4 mfma16(short8 a, short8 b, f32x4 c) {
  return __builtin_amdgcn_mfma_f32_16x16x32_bf16(
      __builtin_bit_cast(bf16x8, a), __builtin_bit_cast(bf16x8, b), c, 0, 0, 0);
}
__device__ inline f32x16 mfma32(short8 a, short8 b, f32x16 c) {
  return __builtin_amdgcn_mfma_f32_32x32x16_bf16(
      __builtin_bit_cast(bf16x8, a), __builtin_bit_cast(bf16x8, b), c, 0, 0, 0);
}

__device__ inline void gload_lds16(void* lds, const void* g) {
  __builtin_amdgcn_global_load_lds(
      (const __attribute__((address_space(1))) unsigned int*)g,
      (__attribute__((address_space(3))) unsigned int*)lds, 16, 0, 0);
}

// ---------------- weight fp32 -> bf16 convert (vectorized) ----------------
__global__ void cvt_kernel(const float4* __restrict__ src, short4v* __restrict__ dst, int n4) {
  int i = blockIdx.x * 256 + threadIdx.x;
  if (i < n4) {
    float4 v = src[i];
    short4v o;
    o[0] = f2bf(v.x); o[1] = f2bf(v.y); o[2] = f2bf(v.z); o[3] = f2bf(v.w);
    dst[i] = o;
  }
}

// ---------------- LayerNorm (optionally double LN) ----------------
__global__ __launch_bounds__(256) void ln_kernel(
    const float* __restrict__ Xin,
    const float* __restrict__ g1, const float* __restrict__ b1,
    const float* __restrict__ g2, const float* __restrict__ b2,
    short* __restrict__ out, int dbl)
{
  const int row = blockIdx.x * 4 + (threadIdx.x >> 6);
  const int lane = threadIdx.x & 63;
  const float4 v = *(const float4*)(Xin + (size_t)row * 256 + lane * 4);
  float y[4] = {v.x, v.y, v.z, v.w};

  float s = y[0] + y[1] + y[2] + y[3];
  #pragma unroll
  for (int m = 32; m >= 1; m >>= 1) s += __shfl_xor(s, m, 64);
  float mean = s * (1.0f / 256.0f);
  float sq = 0.f;
  #pragma unroll
  for (int i = 0; i < 4; ++i) { y[i] -= mean; sq += y[i] * y[i]; }
  #pragma unroll
  for (int m = 32; m >= 1; m >>= 1) sq += __shfl_xor(sq, m, 64);
  float rs = rsqrtf(sq * (1.0f / 256.0f) + 1e-6f);
  #pragma unroll
  for (int i = 0; i < 4; ++i) y[i] = y[i] * rs * g1[lane * 4 + i] + b1[lane * 4 + i];

  if (dbl) {
    float s2 = y[0] + y[1] + y[2] + y[3];
    #pragma unroll
    for (int m = 32; m >= 1; m >>= 1) s2 += __shfl_xor(s2, m, 64);
    float m2 = s2 * (1.0f / 256.0f);
    float sq2 = 0.f;
    #pragma unroll
    for (int i = 0; i < 4; ++i) { y[i] -= m2; sq2 += y[i] * y[i]; }
    #pragma unroll
    for (int m = 32; m >= 1; m >>= 1) sq2 += __shfl_xor(sq2, m, 64);
    float rs2 = rsqrtf(sq2 * (1.0f / 256.0f) + 1e-6f);
    #pragma unroll
    for (int i = 0; i < 4; ++i) y[i] = y[i] * rs2 * g2[lane * 4 + i] + b2[lane * 4 + i];
  }
  #pragma unroll
  for (int i = 0; i < 4; ++i) out[(size_t)row * 256 + lane * 4 + i] = f2bf(y[i]);
}

// ---------------- Q/K l2norm prepass (in place on qkv_bf) ----------------
__global__ __launch_bounds__(256) void qknorm_kernel(short* __restrict__ qkv) {
  const int row = blockIdx.x * 4 + (threadIdx.x >> 6);
  const int lane = threadIdx.x & 63;
  short* p = qkv + (size_t)row * 768 + lane * 8;
  short8 v = *(short8*)p;
  float f[8]; float ss = 0.f;
  #pragma unroll
  for (int j = 0; j < 8; ++j) { f[j] = bf2f(v[j]); ss += f[j] * f[j]; }
  ss += __shfl_xor(ss, 1, 64);
  ss += __shfl_xor(ss, 2, 64);
  float inv = 1.0f / fmaxf(sqrtf(ss), 1e-8f);
  short8 o;
  #pragma unroll
  for (int j = 0; j < 8; ++j) o[j] = f2bf(f[j] * inv);
  *(short8*)p = o;
}

// ---------------- GEMM: C[M,N] = A[M,K] @ Bw[N,K]^T (+epilogue) ----------------
template<int BN, int EPI>
__global__ __launch_bounds__(256) void gemm_bt(
    const short* __restrict__ A, const short* __restrict__ Bw,
    const float* __restrict__ bias, float* __restrict__ X,
    short* __restrict__ Obf, const float* __restrict__ scale_p,
    int M, int N, int K)
{
  constexpr int MI = (BN == 128) ? 4 : 2;
  __shared__ __align__(16) short A_s[128 * 64];
  __shared__ __align__(16) short B_s[BN * 64];
  const int tid = threadIdx.x;
  const int lane = tid & 63;
  const int w = tid >> 6;
  const int lo4 = lane & 15, hi2 = lane >> 4;
  int wm, wn0;
  if (BN == 128) { wm = (w >> 1) * 64; wn0 = (w & 1) * 64; }
  else           { wm = w * 32;        wn0 = 0; }
  const int tM = blockIdx.y * 128, tN = blockIdx.x * BN;

  f32x4 acc[MI][4];
  #pragma unroll
  for (int i = 0; i < MI; ++i)
    #pragma unroll
    for (int j = 0; j < 4; ++j) acc[i][j] = (f32x4){0.f, 0.f, 0.f, 0.f};

  const int swz = (lo4 & 7) << 3;

  for (int k0 = 0; k0 < K; k0 += 64) {
    #pragma unroll
    for (int ri = 0; ri < 4; ++ri) {
      int o = ri * 2048 + tid * 8;
      int row = o >> 6;
      int col = (o & 63) ^ ((row & 7) << 3);
      gload_lds16(&A_s[ri * 2048 + w * 512], A + (size_t)(tM + row) * K + k0 + col);
    }
    #pragma unroll
    for (int ri = 0; ri < BN / 32; ++ri) {
      int o = ri * 2048 + tid * 8;
      int row = o >> 6;
      int col = (o & 63) ^ ((row & 7) << 3);
      gload_lds16(&B_s[ri * 2048 + w * 512], Bw + (size_t)(tN + row) * K + k0 + col);
    }
    __syncthreads();
    #pragma unroll
    for (int kc = 0; kc < 2; ++kc) {
      short8 af[MI], bfr[4];
      #pragma unroll
      for (int i = 0; i < MI; ++i)
        af[i] = *(const short8*)&A_s[(wm + i * 16 + lo4) * 64 + ((kc * 32 + hi2 * 8) ^ swz)];
      #pragma unroll
      for (int j = 0; j < 4; ++j)
        bfr[j] = *(const short8*)&B_s[(wn0 + j * 16 + lo4) * 64 + ((kc * 32 + hi2 * 8) ^ swz)];
      #pragma unroll
      for (int i = 0; i < MI; ++i)
        #pragma unroll
        for (int j = 0; j < 4; ++j)
          acc[i][j] = mfma16(af[i], bfr[j], acc[i][j]);
    }
    __syncthreads();
  }

  float ts = 0.f;
  if (EPI == 1 || EPI == 3) ts = tanhf(scale_p[0]);

  #pragma unroll
  for (int i = 0; i < MI; ++i) {
    #pragma unroll
    for (int j = 0; j < 4; ++j) {
      #pragma unroll
      for (int r = 0; r < 4; ++r) {
        int row = tM + wm + i * 16 + hi2 * 4 + r;
        int col = tN + wn0 + j * 16 + lo4;
        float v = acc[i][j][r] + bias[col];
        size_t idx = (size_t)row * N + col;
        if (EPI == 0) {
          Obf[idx] = f2bf(v);
        } else if (EPI == 1) {
          X[idx] += ts * (v * 0.5f);
        } else if (EPI == 2) {
          float gl = 0.5f * v * (1.0f + erff(v * 0.70710678118f));
          Obf[idx] = f2bf(gl);
        } else {
          float o = X[idx] + ts * v;
          o = fminf(100.f, fmaxf(-100.f, o));
          X[idx] = o;
        }
      }
    }
  }
}

// ---------------- fused causal attention, 32x32 MFMA, swapped QK^T ----------------
// Grid (8,64): block = q-tile of 128 (4 waves x 32 queries). K staged to LDS via
// global_load_lds (source-swizzled), V reg-staged then LDS-transposed (bank-exact
// XOR swizzle), pad precomputed to a 128B LDS bitmask. 1 barrier per k-tile.
__global__ __launch_bounds__(256, 2) void attn_kernel(
    const short* __restrict__ qkv, const unsigned char* __restrict__ pad,
    short* __restrict__ ao)
{
  __shared__ __align__(16) short K_s[2][2048];
  __shared__ __align__(16) short V_s[2][2048];
  __shared__ __align__(8) unsigned char Pm_s[128];

  const float SCALE = 0.17677669529663687f;  // 1/sqrt(32)
  const int tid = threadIdx.x, lane = tid & 63, w = tid >> 6;
  const int lo5 = lane & 31, hi1 = lane >> 5;
  const int qt = blockIdx.x;
  const int bh = blockIdx.y;
  const int b = bh >> 3, h = bh & 7;
  const size_t rowbase = (size_t)b * TT;
  const int qrow = qt * 128 + w * 32 + lo5;
  const int nt = 2 * qt + 2;
  const int maskT = 2 * qt + (w >> 1);

  // pad bitmask: byte i covers keys 8i..8i+7
  if (tid < 128) {
    unsigned long long c = ((const unsigned long long*)(pad + rowbase))[tid];
    unsigned int by = 0;
    #pragma unroll
    for (int j = 0; j < 8; ++j) by |= (unsigned int)((c >> (8 * j)) & 1ull) << j;
    Pm_s[tid] = (unsigned char)by;
  }

  // Q b-frags: lane holds Q[q=lo5][c2*16 + hi1*8 + j]
  short8 qb[2];
  #pragma unroll
  for (int c2 = 0; c2 < 2; ++c2)
    qb[c2] = *(const short8*)(qkv + (rowbase + qrow) * 768 + h * 32 + c2 * 16 + hi1 * 8);

  // staging: thread -> (key = tid>>2, d-group = tid&3)
  const int skey = tid >> 2;
  const int sdg = tid & 3;
  const int sd = sdg * 8;
  // K source pre-swizzled so linear LDS dest yields K_s[key][ (dg^(key&3))*8 .. ]
  const short* Ksrc0 = qkv + (rowbase + skey) * 768 + 256 + h * 32 + ((sdg ^ (skey & 3)) * 8);
  const short* Vsrc0 = qkv + (rowbase + skey) * 768 + 512 + h * 32 + sd;
  // Vt write offsets: addr(key, d) = d*64 + (((key>>3) ^ (d&7) ^ (d>>3)) & 7)*8 + (key&7)
  int vwo[8];
  #pragma unroll
  for (int j = 0; j < 8; ++j)
    vwo[j] = (sd + j) * 64 + ((((skey >> 3) ^ j ^ sdg) & 7) * 8) + (skey & 7);

  gload_lds16(&K_s[0][w * 512], Ksrc0);
  {
    short8 vreg = *(const short8*)Vsrc0;
    #pragma unroll
    for (int j = 0; j < 8; ++j) V_s[0][vwo[j]] = vreg[j];
  }
  __syncthreads();

  f32x16 oaccA = (f32x16)0.0f;
  f32x16 oaccB = (f32x16)0.0f;
  float rsum = 0.f;

  for (int t = 0; t < nt; ++t) {
    const int cur = t & 1, nxt = cur ^ 1;
    short8 vregN;
    const bool pre = (t + 1 < nt);
    if (pre) {
      gload_lds16(&K_s[nxt][w * 512], Ksrc0 + (size_t)(t + 1) * 64 * 768);
      vregN = *(const short8*)(Vsrc0 + (size_t)(t + 1) * 64 * 768);
    }

    if (t <= maskT) {
      // ---- S^T = K·Q^T ----
      f32x16 sa[2];
      #pragma unroll
      for (int kg = 0; kg < 2; ++kg) {
        const int krow = (kg * 32 + lo5) * 32;
        short8 kf0 = *(const short8*)&K_s[cur][krow + ((hi1 ^ (lo5 & 3)) * 8)];
        short8 kf1 = *(const short8*)&K_s[cur][krow + (((2 + hi1) ^ (lo5 & 3)) * 8)];
        f32x16 z = (f32x16)0.0f;
        z = mfma32(kf0, qb[0], z);
        sa[kg] = mfma32(kf1, qb[1], z);
      }
      // ---- softmax numerator ----
      unsigned long long pm = ((const unsigned long long*)Pm_s)[t];
      const bool needMask = (t == maskT);
      const int qrel = qrow - t * 64;
      float p[2][16];
      #pragma unroll
      for (int kg = 0; kg < 2; ++kg) {
        #pragma unroll
        for (int r = 0; r < 16; ++r) {
          float sv = sa[kg][r] * SCALE;
          sv = fminf(10.f, fmaxf(-10.f, sv));
          float pe = __expf(sv);
          int key = kg * 32 + (r & 3) + 8 * (r >> 2) + 4 * hi1;
          if (needMask) pe = (key > qrel) ? 0.f : pe;
          if (pm) pe = ((pm >> key) & 1ull) ? 0.f : pe;
          p[kg][r] = pe;
          rsum += pe;
        }
      }
      // ---- pack to bf16 pairs ----
      unsigned int pk[2][8];
      #pragma unroll
      for (int kg = 0; kg < 2; ++kg)
        #pragma unroll
        for (int i = 0; i < 8; ++i)
          pk[kg][i] = cvtpk(p[kg][2 * i], p[kg][2 * i + 1]);
      // ---- PV ----
      #pragma unroll
      for (int k2 = 0; k2 < 4; ++k2) {
        const int kg = k2 >> 1, half = k2 & 1;
        unsigned int keep0 = hi1 ? pk[kg][4 * half + 2] : pk[kg][4 * half + 0];
        unsigned int keep1 = hi1 ? pk[kg][4 * half + 3] : pk[kg][4 * half + 1];
        unsigned int send0 = hi1 ? pk[kg][4 * half + 0] : pk[kg][4 * half + 2];
        unsigned int send1 = hi1 ? pk[kg][4 * half + 1] : pk[kg][4 * half + 3];
        unsigned int r0 = (unsigned int)__shfl_xor((int)send0, 32, 64);
        unsigned int r1 = (unsigned int)__shfl_xor((int)send1, 32, 64);
        union { unsigned int u[4]; short8 s; } fa;
        fa.u[0] = hi1 ? r0 : keep0;
        fa.u[1] = hi1 ? r1 : keep1;
        fa.u[2] = hi1 ? keep0 : r0;
        fa.u[3] = hi1 ? keep1 : r1;
        // V b-frag: one swizzled ds_read_b128 (conflict-free)
        const int g = ((k2 * 2 + hi1) ^ (lo5 & 7) ^ (lo5 >> 3)) & 7;
        short8 vb = *(const short8*)&V_s[cur][lo5 * 64 + g * 8];
        if (k2 & 1) oaccB = mfma32(fa.s, vb, oaccB);
        else        oaccA = mfma32(fa.s, vb, oaccA);
      }
    }

    if (pre) {
      #pragma unroll
      for (int j = 0; j < 8; ++j) V_s[nxt][vwo[j]] = vregN[j];
    }
    __syncthreads();
  }

  // ---- finalize ----
  rsum += __shfl_xor(rsum, 32, 64);
  float rinv = 1.0f / fmaxf(rsum, 1e-30f);
  #pragma unroll
  for (int r = 0; r < 16; ++r) {
    int ql = (r & 3) + 8 * (r >> 2) + 4 * hi1;
    float riv = __shfl(rinv, ql, 64);
    int qg = qt * 128 + w * 32 + ql;
    ao[(rowbase + qg) * 256 + h * 32 + lo5] = f2bf((oaccA[r] + oaccB[r]) * riv);
  }
}

extern "C" void kernel_launch(void* const* d_in, const int* in_sizes, int n_in,
                              void* d_out, int out_size, void* d_ws, size_t ws_size,
                              hipStream_t stream) {
  const float* x_in  = (const float*)d_in[0];
  const unsigned char* pad = (const unsigned char*)d_in[1];
  const float* ln1_g = (const float*)d_in[2];
  const float* ln1_b = (const float*)d_in[3];
  const float* qn_g  = (const float*)d_in[4];
  const float* qn_b  = (const float*)d_in[5];
  const float* Wqkv  = (const float*)d_in[6];
  const float* bqkv  = (const float*)d_in[7];
  const float* Wo    = (const float*)d_in[8];
  const float* bo    = (const float*)d_in[9];
  const float* ln2_g = (const float*)d_in[10];
  const float* ln2_b = (const float*)d_in[11];
  const float* W1    = (const float*)d_in[12];
  const float* b1    = (const float*)d_in[13];
  const float* W2    = (const float*)d_in[14];
  const float* b2    = (const float*)d_in[15];
  const float* alpha = (const float*)d_in[16];
  const float* beta  = (const float*)d_in[17];

  char* ws = (char*)d_ws;
  size_t off = 0;
  short* wqkv_bf = (short*)(ws + off); off += (size_t)4 * 768 * 256 * 2;
  short* wo_bf   = (short*)(ws + off); off += (size_t)4 * 256 * 256 * 2;
  short* w1_bf   = (short*)(ws + off); off += (size_t)4 * 1024 * 256 * 2;
  short* w2_bf   = (short*)(ws + off); off += (size_t)4 * 256 * 1024 * 2;
  short* h_bf    = (short*)(ws + off); off += (size_t)BT * 256 * 2;
  short* qkv_bf  = (short*)(ws + off); off += (size_t)BT * 768 * 2;
  short* ao_bf   = (short*)(ws + off); off += (size_t)BT * 256 * 2;
  short* g_bf    = (short*)(ws + off); off += (size_t)BT * 1024 * 2;

  float* X = (float*)d_out;

  hipMemcpyAsync(d_out, x_in, (size_t)BT * DD * 4, hipMemcpyDeviceToDevice, stream);
  cvt_kernel<<<768,  256, 0, stream>>>((const float4*)Wqkv, (short4v*)wqkv_bf, 4 * 768 * 256 / 4);
  cvt_kernel<<<256,  256, 0, stream>>>((const float4*)Wo,   (short4v*)wo_bf,   4 * 256 * 256 / 4);
  cvt_kernel<<<1024, 256, 0, stream>>>((const float4*)W1,   (short4v*)w1_bf,   4 * 1024 * 256 / 4);
  cvt_kernel<<<1024, 256, 0, stream>>>((const float4*)W2,   (short4v*)w2_bf,   4 * 256 * 1024 / 4);

  for (int l = 0; l < 4; ++l) {
    ln_kernel<<<2048, 256, 0, stream>>>(X, ln1_g + l * 256, ln1_b + l * 256,
                                        qn_g + l * 256, qn_b + l * 256, h_bf, 1);
    gemm_bt<128, 0><<<dim3(6, 64), 256, 0, stream>>>(h_bf, wqkv_bf + (size_t)l * 768 * 256,
                                                     bqkv + l * 768, nullptr, qkv_bf, nullptr,
                                                     8192, 768, 256);
    qknorm_kernel<<<2048, 256, 0, stream>>>(qkv_bf);
    attn_kernel<<<dim3(8, 64), 256, 0, stream>>>(qkv_bf, pad, ao_bf);
    gemm_bt<64, 1><<<dim3(4, 64), 256, 0, stream>>>(ao_bf, wo_bf + (size_t)l * 256 * 256,
                                                    bo + l * 256, X, nullptr, alpha + l,
                                                    8192, 256, 256);
    ln_kernel<<<2048, 256, 0, stream>>>(X, ln2_g + l * 256, ln2_b + l * 256,
                                        nullptr, nullptr, h_bf, 0);
    gemm_bt<128, 2><<<dim3(8, 64), 256, 0, stream>>>(h_bf, w1_bf + (size_t)l * 1024 * 256,
                                                     b1 + l * 1024, nullptr, g_bf, nullptr,
                                                     8192, 1024, 256);
    gemm_bt<64, 3><<<dim3(4, 64), 256, 0, stream>>>(g_bf, w2_bf + (size_t)l * 256 * 1024,
                                                    b2 + l * 256, X, nullptr, beta + l,
                                                    8192, 256, 1024);
  }
}